// Round 1
// baseline (123.499 us; speedup 1.0000x reference)
//
#include <hip/hip_runtime.h>
#include <math.h>

#define B_    8
#define Q_    900
#define NCLS_ 11
#define NANC_ 100
#define H_    200
#define W_    200
#define C_    256

// ---------------------------------------------------------------------------
// Kernel 1: scores + rank-based top-k + box->pixel coords (one block per batch)
// ---------------------------------------------------------------------------
__global__ __launch_bounds__(1024) void segdet_topk_kernel(
    const float* __restrict__ pred_boxes,   // [B,Q,4]
    const float* __restrict__ pred_logits,  // [B,Q,NCLS]
    const float* __restrict__ view,         // [B,5,5]
    int*  __restrict__ ws_idx,              // [B,NANC]  selected q index
    int4* __restrict__ ws_box)              // [B,NANC]  (x0,y0,x1,y1) clipped ints
{
    const int b = blockIdx.x;
    const int q = threadIdx.x;

    __shared__ float sc[Q_];

    if (q < Q_) {
        const float* l = pred_logits + (b * Q_ + q) * NCLS_;
        float v[NCLS_];
        float m = -INFINITY;
        #pragma unroll
        for (int i = 0; i < NCLS_; ++i) { v[i] = l[i]; m = fmaxf(m, v[i]); }
        float s = 0.0f, e10 = -INFINITY;
        #pragma unroll
        for (int i = 0; i < NCLS_; ++i) {
            float e = expf(v[i] - m);
            s += e;
            if (i < NCLS_ - 1) e10 = fmaxf(e10, e);   // exclude background (last)
        }
        sc[q] = e10 / s;
    }
    __syncthreads();

    if (q < Q_) {
        const float my = sc[q];
        int rank = 0;
        for (int j = 0; j < Q_; ++j) {
            float o = sc[j];
            rank += (o > my) || (o == my && j < q);   // top_k tie-break: lower idx first
        }
        if (rank < NANC_) {
            // box -> xyxy -> view transform -> trunc int -> clip.
            // Done in double so int-truncation boundaries match the reference.
            const float* bx = pred_boxes + (b * Q_ + q) * 4;
            double cx = (double)bx[0], cy = (double)bx[1];
            double w  = exp((double)bx[2]);
            double h  = exp((double)bx[3]);
            double p[5] = { cx - 0.5 * w, cy - 0.5 * h,
                            cx + 0.5 * w, cy + 0.5 * h, 1.0 };
            const float* v5 = view + b * 25;
            int ico[4];
            #pragma unroll
            for (int i = 0; i < 4; ++i) {
                double acc = 0.0;
                #pragma unroll
                for (int j = 0; j < 5; ++j) acc += (double)v5[i * 5 + j] * p[j];
                ico[i] = (int)acc;                    // trunc toward zero == astype(int32)
            }
            int x0 = min(max(ico[0], 0), W_);
            int y0 = min(max(ico[1], 0), H_);
            int x1 = min(max(ico[2], 0), W_);
            int y1 = min(max(ico[3], 0), H_);
            const int slot = b * NANC_ + rank;        // rank is unique -> no atomics
            ws_idx[slot] = q;
            ws_box[slot] = make_int4(x0, y0, x1, y1);
        }
    }
}

// ---------------------------------------------------------------------------
// Kernel 2: BEV splat. One block per (b, h) row, 256 threads = 256 channels.
// Sliding-window over w with start/end event buckets (built by thread 0).
// ---------------------------------------------------------------------------
__global__ __launch_bounds__(256) void segdet_bev_kernel(
    const float* __restrict__ box_feats,    // [B,Q,C]
    const int*   __restrict__ ws_idx,       // [B,NANC]
    const int4*  __restrict__ ws_box,       // [B,NANC]
    float* __restrict__ bev,                // [B,H,W,C]
    float* __restrict__ mask)               // [B,H,W] (0/1 floats)
{
    const int b = blockIdx.x / H_;
    const int h = blockIdx.x % H_;
    const int c = threadIdx.x;

    __shared__ int s_q[NANC_];              // selected q of row-active anchor
    __shared__ int head_start[W_ + 1];      // bucket heads by x0
    __shared__ int head_end[W_ + 1];        // bucket heads by x1
    __shared__ int nxt_s[NANC_];
    __shared__ int nxt_e[NANC_];

    if (c <= W_) { head_start[c] = -1; head_end[c] = -1; }
    __syncthreads();

    if (c == 0) {
        int nrow = 0;
        for (int k = 0; k < NANC_; ++k) {
            int4 bxk = ws_box[b * NANC_ + k];
            // active on this row and non-empty in x
            if (bxk.y <= h && h < bxk.w && bxk.x < bxk.z) {
                int r = nrow++;
                s_q[r] = ws_idx[b * NANC_ + k];
                nxt_s[r] = head_start[bxk.x]; head_start[bxk.x] = r;
                nxt_e[r] = head_end[bxk.z];   head_end[bxk.z]   = r;
            }
        }
    }
    __syncthreads();

    const float* fb = box_feats + (size_t)b * Q_ * C_ + c;
    float* orow = bev + ((size_t)(b * H_ + h) * W_) * C_ + c;
    float* mrow = mask + (size_t)(b * H_ + h) * W_;

    float acc = 0.0f;
    int cnt = 0;
    for (int w = 0; w < W_; ++w) {
        // close boxes ending at w, then open boxes starting at w
        for (int e = head_end[w]; e != -1; e = nxt_e[e]) {
            acc -= fb[s_q[e] * C_];
            --cnt;
        }
        for (int e = head_start[w]; e != -1; e = nxt_s[e]) {
            acc += fb[s_q[e] * C_];
            ++cnt;
        }
        if (cnt == 0) acc = 0.0f;           // exact zero outside coverage, kills drift
        orow[(size_t)w * C_] = acc;
        if (c == 0) mrow[w] = (cnt > 0) ? 1.0f : 0.0f;
    }
}

// ---------------------------------------------------------------------------
extern "C" void kernel_launch(void* const* d_in, const int* in_sizes, int n_in,
                              void* d_out, int out_size, void* d_ws, size_t ws_size,
                              hipStream_t stream) {
    const float* pred_boxes  = (const float*)d_in[0];
    const float* pred_logits = (const float*)d_in[1];
    const float* box_feats   = (const float*)d_in[2];
    const float* view        = (const float*)d_in[3];

    float* bev  = (float*)d_out;
    float* mask = bev + (size_t)B_ * H_ * W_ * C_;

    int*  ws_idx = (int*)d_ws;                            // 800 ints = 3200 B
    int4* ws_box = (int4*)((char*)d_ws + 3200);           // 800 int4 = 12800 B (16B aligned)

    segdet_topk_kernel<<<B_, 1024, 0, stream>>>(pred_boxes, pred_logits, view,
                                                ws_idx, ws_box);
    segdet_bev_kernel<<<B_ * H_, 256, 0, stream>>>(box_feats, ws_idx, ws_box,
                                                   bev, mask);
}